// Round 10
// baseline (90.963 us; speedup 1.0000x reference)
//
#include <hip/hip_runtime.h>
#include <math.h>

#define A_N 2048
#define L_N 512
#define D 128
#define B_N 64
#define H1_N 512
#define H2_N 256
#define NCHUNK 16
#define CL 32     // residues per k2 block
#define PST 136   // ushort LDS row stride

typedef __attribute__((ext_vector_type(8))) short short8;
typedef __attribute__((ext_vector_type(4))) float f32x4;

__device__ __forceinline__ int lb_dev(const int* __restrict__ arr, int n, int val) {
    int lo = 0, hi = n;
    while (lo < hi) { int mid = (lo + hi) >> 1; if (arr[mid] < val) lo = mid + 1; else hi = mid; }
    return lo;
}

__device__ __forceinline__ float blk_sum(float v, float* red, int tid) {
    #pragma unroll
    for (int off = 32; off >= 1; off >>= 1) v += __shfl_xor(v, off);
    __syncthreads();
    if ((tid & 63) == 0) red[tid >> 6] = v;
    __syncthreads();
    return red[0] + red[1] + red[2] + red[3];
}

__device__ __forceinline__ unsigned short f2bf(float f) {
    unsigned int u = __float_as_uint(f);
    return (unsigned short)((u + 0x7FFFu + ((u >> 16) & 1u)) >> 16);
}
__device__ __forceinline__ float bf2f(unsigned short h) {
    return __uint_as_float(((unsigned int)h) << 16);
}

// ---------- K0: init segoff, cnt, out ----------
__global__ __launch_bounds__(256) void k0_init(const int* __restrict__ splits,
                                               const float* __restrict__ bo,
                                               int* __restrict__ segoff,
                                               int* __restrict__ cnt,
                                               float* __restrict__ out) {
    const int tid = threadIdx.x;
    if (tid <= B_N) segoff[tid] = lb_dev(splits, A_N, tid);
    if (tid < B_N) { cnt[tid] = 0; out[tid] = bo[0]; }
}

// ---------- K2: fused X-GEMM + scores + last-arrival pools -> HcT ----------
// grid = 64 molecules x 16 chunks
__global__ __launch_bounds__(256, 2) void k2_fused(const float* __restrict__ atom_embed,
                                                   const float* __restrict__ prot,
                                                   const float* __restrict__ W_att,
                                                   const int* __restrict__ segoff,
                                                   float* __restrict__ rowmaxp,
                                                   float* __restrict__ ppart,
                                                   float* __restrict__ eWpart,
                                                   float* __restrict__ HcT,
                                                   int* __restrict__ cnt) {
    __shared__ unsigned short Xs_h[32 * PST], Xs_l[32 * PST];
    __shared__ float rm_part[2][32];
    __shared__ float cm_part[2][32];
    __shared__ float ews_s[CL];
    __shared__ float4 pred[8][32];
    __shared__ float coef[256];
    __shared__ float red[4];
    __shared__ int isLast;

    const int tid = threadIdx.x;
    const int bid = blockIdx.x;
    const int b = bid & (B_N - 1);
    const int chunk = bid >> 6;           // 0..15
    const int l0 = chunk * CL;

    const int lane = tid & 63;
    const int w = tid >> 6;               // wave 0..3
    const int col = lane & 15;
    const int kb = lane >> 4;             // 0..3
    const int lt = w & 1;                 // l-tile 0/1 (scores)
    const int pair = w >> 1;              // atom-row-tile 0/1 (scores)

    // P B-frags: prot rows l0+lt*16+col, split hi/lo (persist across whole kernel)
    short8 PBh[4], PBl[4];
    {
        const float4* pb = (const float4*)(prot + ((size_t)(b * L_N + l0 + lt * 16 + col)) * D);
        #pragma unroll
        for (int ks = 0; ks < 4; ++ks) {
            const float4 v0 = pb[ks * 8 + kb * 2];
            const float4 v1 = pb[ks * 8 + kb * 2 + 1];
            const float vv[8] = {v0.x, v0.y, v0.z, v0.w, v1.x, v1.y, v1.z, v1.w};
            short8 bh, bl;
            #pragma unroll
            for (int j = 0; j < 8; ++j) {
                const unsigned short h = f2bf(vv[j]);
                bh[j] = (short)h;
                bl[j] = (short)f2bf(vv[j] - bf2f(h));
            }
            PBh[ks] = bh; PBl[ks] = bl;
        }
    }
    const int s = segoff[b];
    const int n = segoff[b + 1] - s;

    float cmrun = -INFINITY;
    for (int a0 = 0; a0 < n; a0 += 32) {
        __syncthreads();   // Xs / rm_part free from previous iteration

        // ---- X phase: X[a0..a0+32) = atom_embed @ W_att (split-bf16 MFMA) ----
        {
            // W_att B-frags: wave w owns d-coltiles {2w, 2w+1} (L1-hot scalar gather)
            short8 WBh[2][4], WBl[2][4];
            #pragma unroll
            for (int ct = 0; ct < 2; ++ct) {
                const int dcol = (w * 2 + ct) * 16 + col;
                #pragma unroll
                for (int ks = 0; ks < 4; ++ks) {
                    short8 bh, bl;
                    #pragma unroll
                    for (int j = 0; j < 8; ++j) {
                        const float wv = W_att[(size_t)(ks * 32 + kb * 8 + j) * D + dcol];
                        const unsigned short h = f2bf(wv);
                        bh[j] = (short)h;
                        bl[j] = (short)f2bf(wv - bf2f(h));
                    }
                    WBh[ct][ks] = bh; WBl[ct][ks] = bl;
                }
            }
            #pragma unroll
            for (int m = 0; m < 2; ++m) {
                const int ar = min(s + a0 + m * 16 + col, A_N - 1);
                short8 Ah[4], Al[4];
                #pragma unroll
                for (int ks = 0; ks < 4; ++ks) {
                    const float4* p = (const float4*)(atom_embed + (size_t)ar * D) + ks * 8 + kb * 2;
                    const float4 v0 = p[0];
                    const float4 v1 = p[1];
                    const float vv[8] = {v0.x, v0.y, v0.z, v0.w, v1.x, v1.y, v1.z, v1.w};
                    short8 ah, al;
                    #pragma unroll
                    for (int j = 0; j < 8; ++j) {
                        const unsigned short h = f2bf(vv[j]);
                        ah[j] = (short)h;
                        al[j] = (short)f2bf(vv[j] - bf2f(h));
                    }
                    Ah[ks] = ah; Al[ks] = al;
                }
                #pragma unroll
                for (int ct = 0; ct < 2; ++ct) {
                    f32x4 aHH = {0.f, 0.f, 0.f, 0.f};
                    f32x4 aHL = {0.f, 0.f, 0.f, 0.f};
                    f32x4 aLH = {0.f, 0.f, 0.f, 0.f};
                    #pragma unroll
                    for (int ks = 0; ks < 4; ++ks) {
                        aHH = __builtin_amdgcn_mfma_f32_16x16x32_bf16(Ah[ks], WBh[ct][ks], aHH, 0, 0, 0);
                        aHL = __builtin_amdgcn_mfma_f32_16x16x32_bf16(Ah[ks], WBl[ct][ks], aHL, 0, 0, 0);
                        aLH = __builtin_amdgcn_mfma_f32_16x16x32_bf16(Al[ks], WBh[ct][ks], aLH, 0, 0, 0);
                    }
                    const int dcol = (w * 2 + ct) * 16 + col;
                    #pragma unroll
                    for (int i = 0; i < 4; ++i) {
                        const float xv = aHH[i] + aHL[i] + aLH[i];
                        const int row = m * 16 + kb * 4 + i;
                        const unsigned short h = f2bf(xv);
                        Xs_h[row * PST + dcol] = h;
                        Xs_l[row * PST + dcol] = f2bf(xv - bf2f(h));
                    }
                }
            }
        }
        __syncthreads();

        // ---- score phase: S-tile = X-tile . P^T ----
        {
            short8 Ah[4], Al[4];
            const int xrow = pair * 16 + col;
            #pragma unroll
            for (int ks = 0; ks < 4; ++ks) {
                Ah[ks] = *(const short8*)(Xs_h + xrow * PST + ks * 32 + kb * 8);
                Al[ks] = *(const short8*)(Xs_l + xrow * PST + ks * 32 + kb * 8);
            }
            f32x4 aHH = {0.f, 0.f, 0.f, 0.f};
            f32x4 aHL = {0.f, 0.f, 0.f, 0.f};
            f32x4 aLH = {0.f, 0.f, 0.f, 0.f};
            #pragma unroll
            for (int ks = 0; ks < 4; ++ks) {
                aHH = __builtin_amdgcn_mfma_f32_16x16x32_bf16(Ah[ks], PBh[ks], aHH, 0, 0, 0);
                aHL = __builtin_amdgcn_mfma_f32_16x16x32_bf16(Ah[ks], PBl[ks], aHL, 0, 0, 0);
                aLH = __builtin_amdgcn_mfma_f32_16x16x32_bf16(Al[ks], PBh[ks], aLH, 0, 0, 0);
            }
            float r[4];
            #pragma unroll
            for (int i = 0; i < 4; ++i) r[i] = aHH[i] + aHL[i] + aLH[i];

            // rowmax over this wave's 16 l's
            float r0 = r[0], r1 = r[1], r2 = r[2], r3 = r[3];
            #pragma unroll
            for (int off = 1; off <= 8; off <<= 1) {
                r0 = fmaxf(r0, __shfl_xor(r0, off));
                r1 = fmaxf(r1, __shfl_xor(r1, off));
                r2 = fmaxf(r2, __shfl_xor(r2, off));
                r3 = fmaxf(r3, __shfl_xor(r3, off));
            }
            if (col == 0) {
                rm_part[lt][pair * 16 + kb * 4 + 0] = r0;
                rm_part[lt][pair * 16 + kb * 4 + 1] = r1;
                rm_part[lt][pair * 16 + kb * 4 + 2] = r2;
                rm_part[lt][pair * 16 + kb * 4 + 3] = r3;
            }
            // colmax over valid atoms
            const int rb = a0 + pair * 16 + kb * 4;
            float cm = -INFINITY;
            if (rb + 0 < n) cm = fmaxf(cm, r[0]);
            if (rb + 1 < n) cm = fmaxf(cm, r[1]);
            if (rb + 2 < n) cm = fmaxf(cm, r[2]);
            if (rb + 3 < n) cm = fmaxf(cm, r[3]);
            cm = fmaxf(cm, __shfl_xor(cm, 16));
            cm = fmaxf(cm, __shfl_xor(cm, 32));
            cmrun = fmaxf(cmrun, cm);
        }
        __syncthreads();
        if (tid < 32 && a0 + tid < n)
            rowmaxp[(size_t)(s + a0 + tid) * NCHUNK + chunk] =
                fmaxf(rm_part[0][tid], rm_part[1][tid]);
    }

    // ---- chunk epilogue: ews, eW partial, prot-pool partial ----
    if (kb == 0) cm_part[pair][lt * 16 + col] = cmrun;
    __syncthreads();
    if (tid < CL) ews_s[tid] = expf(fmaxf(cm_part[0][tid], cm_part[1][tid]));
    __syncthreads();
    if (tid < 32) {
        float v = ews_s[tid];
        #pragma unroll
        for (int off = 1; off <= 16; off <<= 1) v += __shfl_xor(v, off);
        if (tid == 0) eWpart[b * NCHUNK + chunk] = v;
    }
    const int rg = tid >> 5, c4 = tid & 31;
    {
        float4 pp4 = {0.f, 0.f, 0.f, 0.f};
        const float4* src = (const float4*)(prot + ((size_t)b * L_N + l0) * D);
        #pragma unroll
        for (int q = 0; q < 4; ++q) {
            const int i = tid + q * 256;
            const float4 v = src[i];
            const float wgt = ews_s[i >> 5];
            pp4.x += wgt * v.x; pp4.y += wgt * v.y;
            pp4.z += wgt * v.z; pp4.w += wgt * v.w;
        }
        pred[rg][c4] = pp4;
    }
    __syncthreads();
    if (tid < 32) {
        float4 acc = pred[0][tid];
        #pragma unroll
        for (int gg = 1; gg < 8; ++gg) {
            const float4 t = pred[gg][tid];
            acc.x += t.x; acc.y += t.y; acc.z += t.z; acc.w += t.w;
        }
        float* dst = ppart + (size_t)(b * NCHUNK + chunk) * D + tid * 4;
        dst[0] = acc.x; dst[1] = acc.y; dst[2] = acc.z; dst[3] = acc.w;
    }
    __syncthreads();

    // ---- last-arrival: 16th block of molecule b does the pools ----
    // (blocks b+64*chunk are all == b mod 8 -> same XCD -> L2-visible to each other)
    if (tid == 0) {
        __threadfence();
        int old = __hip_atomic_fetch_add(&cnt[b], 1, __ATOMIC_ACQ_REL, __HIP_MEMORY_SCOPE_AGENT);
        isLast = (old == NCHUNK - 1) ? 1 : 0;
    }
    __syncthreads();
    if (!isLast) return;
    if (tid == 0) __threadfence();
    __syncthreads();

    // Sc = sum_a exp(max over chunks)
    float local = 0.f;
    for (int j = tid; j < n; j += 256) {
        const float* rp = rowmaxp + (size_t)(s + j) * NCHUNK;
        float m = rp[0];
        #pragma unroll
        for (int c = 1; c < NCHUNK; ++c) m = fmaxf(m, rp[c]);
        local += expf(m);
    }
    const float Sc = blk_sum(local, red, tid);

    // atom pool
    const float4* ae4 = (const float4*)atom_embed;
    float4 pool = {0.f, 0.f, 0.f, 0.f};
    for (int t0 = 0; t0 < n; t0 += 256) {
        const int cnt2 = min(256, n - t0);
        __syncthreads();
        for (int j = tid; j < cnt2; j += 256) {
            const float* rp = rowmaxp + (size_t)(s + t0 + j) * NCHUNK;
            float m = rp[0];
            #pragma unroll
            for (int c = 1; c < NCHUNK; ++c) m = fmaxf(m, rp[c]);
            coef[j] = expf(m) / Sc;
        }
        __syncthreads();
        for (int j = rg; j < cnt2; j += 8) {
            const float c = coef[j];
            const float4 v = ae4[(size_t)(s + t0 + j) * (D / 4) + c4];
            pool.x += c * v.x; pool.y += c * v.y; pool.z += c * v.z; pool.w += c * v.w;
        }
    }
    __syncthreads();
    pred[rg][c4] = pool;
    __syncthreads();
    if (rg == 0) {
        float4 acc = pred[0][c4];
        #pragma unroll
        for (int gg = 1; gg < 8; ++gg) {
            const float4 t = pred[gg][c4];
            acc.x += t.x; acc.y += t.y; acc.z += t.z; acc.w += t.w;
        }
        HcT[(size_t)(c4 * 4 + 0) * B_N + b] = acc.x;
        HcT[(size_t)(c4 * 4 + 1) * B_N + b] = acc.y;
        HcT[(size_t)(c4 * 4 + 2) * B_N + b] = acc.z;
        HcT[(size_t)(c4 * 4 + 3) * B_N + b] = acc.w;
    }
    if (tid < 128) {
        float v = 0.f, ez = 0.f;
        #pragma unroll
        for (int c = 0; c < NCHUNK; ++c) {
            v  += ppart[(size_t)(b * NCHUNK + c) * D + tid];
            ez += eWpart[b * NCHUNK + c];
        }
        HcT[(size_t)(D + tid) * B_N + b] = v / ez;
    }
}

// ---------- K4: H1T = relu(Hc @ W1 + b1)^T ----------
__global__ __launch_bounds__(256) void k4_h1(const float* __restrict__ HcT,
                                             const float* __restrict__ W1,
                                             const float* __restrict__ b1,
                                             float* __restrict__ H1T) {
    __shared__ float hr[4][64];
    const int tid = threadIdx.x;
    const int m = tid & 63;
    const int jh = (tid >> 6) & 1;
    const int kh = tid >> 7;
    const int j = blockIdx.x * 2 + jh;
    float acc = 0.f;
    const int k0 = kh * 128;
    #pragma unroll 8
    for (int k = k0; k < k0 + 128; ++k)
        acc += HcT[(size_t)k * B_N + m] * W1[(size_t)k * H1_N + j];
    hr[jh * 2 + kh][m] = acc;
    __syncthreads();
    if (kh == 0)
        H1T[(size_t)j * B_N + m] = fmaxf(hr[jh * 2][m] + hr[jh * 2 + 1][m] + b1[j], 0.f);
}

// ---------- K5: H2 + output atomics ----------
__global__ __launch_bounds__(256) void k5_h2(const float* __restrict__ H1T,
                                             const float* __restrict__ W2,
                                             const float* __restrict__ b2,
                                             const float* __restrict__ Wo,
                                             float* __restrict__ out) {
    __shared__ float hr[4][64];
    const int tid = threadIdx.x;
    const int m = tid & 63;
    const int kq = tid >> 6;
    const int j = blockIdx.x;
    float acc = 0.f;
    const int k0 = kq * 128;
    #pragma unroll 8
    for (int k = k0; k < k0 + 128; ++k)
        acc += H1T[(size_t)k * B_N + m] * W2[(size_t)k * H2_N + j];
    hr[kq][m] = acc;
    __syncthreads();
    if (kq == 0) {
        const float h2 = fmaxf(hr[0][m] + hr[1][m] + hr[2][m] + hr[3][m] + b2[j], 0.f);
        atomicAdd(out + m, h2 * Wo[j]);
    }
}

extern "C" void kernel_launch(void* const* d_in, const int* in_sizes, int n_in,
                              void* d_out, int out_size, void* d_ws, size_t ws_size,
                              hipStream_t stream) {
    const float* atom_embed = (const float*)d_in[0];
    const float* prot       = (const float*)d_in[1];
    const int*   splits     = (const int*)d_in[2];
    const float* W_att      = (const float*)d_in[3];
    const float* W1         = (const float*)d_in[4];
    const float* b1         = (const float*)d_in[5];
    const float* W2         = (const float*)d_in[6];
    const float* b2         = (const float*)d_in[7];
    const float* Wo         = (const float*)d_in[8];
    const float* bo         = (const float*)d_in[9];
    float* out = (float*)d_out;

    float* fp      = (float*)d_ws;
    float* rowmaxp = fp;  fp += (size_t)A_N * NCHUNK;          // 32768 f
    float* ppart   = fp;  fp += (size_t)B_N * NCHUNK * D;      // 131072 f
    float* eWpart  = fp;  fp += B_N * NCHUNK;                  // 1024 f
    float* HcT     = fp;  fp += 2 * D * B_N;                   // 16384 f
    float* H1T     = fp;  fp += H1_N * B_N;                    // 32768 f
    int*   segoff  = (int*)fp;  fp += 96;                      // 65 ints used, 96 reserved
    int*   cnt     = (int*)fp;  fp += 64;                      // 64 ints (no overlap!)

    hipLaunchKernelGGL(k0_init,  dim3(1),             dim3(256), 0, stream,
                       splits, bo, segoff, cnt, out);
    hipLaunchKernelGGL(k2_fused, dim3(B_N * NCHUNK),  dim3(256), 0, stream,
                       atom_embed, prot, W_att, segoff, rowmaxp, ppart, eWpart, HcT, cnt);
    hipLaunchKernelGGL(k4_h1,    dim3(H1_N / 2),      dim3(256), 0, stream, HcT, W1, b1, H1T);
    hipLaunchKernelGGL(k5_h2,    dim3(H2_N),          dim3(256), 0, stream, H1T, W2, b2, Wo, out);
}

// Round 11
// 47.105 us; speedup vs baseline: 1.9311x; 1.9311x over previous
//
#include <hip/hip_runtime.h>
#include <math.h>

#define A_N 2048
#define L_N 512
#define D 128
#define B_N 64
#define H1_N 512
#define H2_N 256
#define NCHUNK 16

typedef __attribute__((ext_vector_type(8))) short short8;
typedef __attribute__((ext_vector_type(4))) float f32x4;

__device__ __forceinline__ int lb_dev(const int* __restrict__ arr, int n, int val) {
    int lo = 0, hi = n;
    while (lo < hi) { int mid = (lo + hi) >> 1; if (arr[mid] < val) lo = mid + 1; else hi = mid; }
    return lo;
}

__device__ __forceinline__ float blk_sum(float v, float* red, int tid) {
    #pragma unroll
    for (int off = 32; off >= 1; off >>= 1) v += __shfl_xor(v, off);
    __syncthreads();
    if ((tid & 63) == 0) red[tid >> 6] = v;
    __syncthreads();
    return red[0] + red[1] + red[2] + red[3];
}

__device__ __forceinline__ unsigned short f2bf(float f) {
    unsigned int u = __float_as_uint(f);
    return (unsigned short)((u + 0x7FFFu + ((u >> 16) & 1u)) >> 16);
}
__device__ __forceinline__ float bf2f(unsigned short h) {
    return __uint_as_float(((unsigned int)h) << 16);
}

// ---------- K1: X = atom_embed @ W_att -> Xh/Xl ; block0: segoff + out ----------
__global__ __launch_bounds__(256) void k1_xmul(const float* __restrict__ atom_embed,
                                               const float* __restrict__ W_att,
                                               const float* __restrict__ bo,
                                               const int* __restrict__ splits,
                                               unsigned short* __restrict__ Xh,
                                               unsigned short* __restrict__ Xl,
                                               float* __restrict__ out,
                                               int* __restrict__ segoff) {
    __shared__ float ae[8][128];
    const int tid = threadIdx.x;
    const int bid = blockIdx.x;
    if (bid == 0) {
        if (tid <= B_N) segoff[tid] = lb_dev(splits, A_N, tid);
        if (tid < B_N) out[tid] = bo[0];
    }
    const int a0 = bid * 8;
    float4 v = reinterpret_cast<const float4*>(atom_embed + (size_t)a0 * D)[tid];
    const int fi = tid * 4;
    *reinterpret_cast<float4*>(&ae[fi >> 7][fi & 127]) = v;
    __syncthreads();
    const int d = tid & 127;
    const int ai = tid >> 7;
    float acc0 = 0.f, acc1 = 0.f, acc2 = 0.f, acc3 = 0.f;
    #pragma unroll 16
    for (int k = 0; k < D; ++k) {
        const float w = W_att[k * D + d];
        acc0 += ae[ai + 0][k] * w;
        acc1 += ae[ai + 2][k] * w;
        acc2 += ae[ai + 4][k] * w;
        acc3 += ae[ai + 6][k] * w;
    }
    float accs[4] = {acc0, acc1, acc2, acc3};
    #pragma unroll
    for (int t = 0; t < 4; ++t) {
        const size_t idx = (size_t)(a0 + ai + 2 * t) * D + d;
        const unsigned short h = f2bf(accs[t]);
        Xh[idx] = h;
        Xl[idx] = f2bf(accs[t] - bf2f(h));
    }
}

// ---------- K2: barrier-free wave-parallel MFMA scores ----------
// 512 blocks x 4 independent waves = 2048 waves; wave = (b, chunk, tile-parity t0)
__global__ __launch_bounds__(256) void k2_scores(const unsigned short* __restrict__ Xh,
                                                 const unsigned short* __restrict__ Xl,
                                                 const float* __restrict__ prot,
                                                 const int* __restrict__ segoff,
                                                 float* __restrict__ rowmaxp,
                                                 float* __restrict__ cmaxp) {
    const int tid = threadIdx.x;
    const int bid = blockIdx.x;
    const int b = bid & (B_N - 1);                 // bid%8 == b%8 -> per-molecule XCD locality
    const int unit = (bid >> 6) * 4 + (tid >> 6);  // 0..31
    const int chunk = unit & 15;
    const int t0 = unit >> 4;                      // 0..1
    const int lane = tid & 63;
    const int col = lane & 15;
    const int kb = lane >> 4;
    const int l0 = chunk * 32;

    // B-frags for 2 l-tiles, loaded once (unrolled -> 16 loads in flight)
    short8 Bh[2][4], Bl[2][4];
    #pragma unroll
    for (int lt = 0; lt < 2; ++lt) {
        const float4* pb = (const float4*)(prot + ((size_t)(b * L_N + l0 + lt * 16 + col)) * D);
        #pragma unroll
        for (int ks = 0; ks < 4; ++ks) {
            const float4 v0 = pb[ks * 8 + kb * 2];
            const float4 v1 = pb[ks * 8 + kb * 2 + 1];
            const float vv[8] = {v0.x, v0.y, v0.z, v0.w, v1.x, v1.y, v1.z, v1.w};
            short8 bh, bl;
            #pragma unroll
            for (int j = 0; j < 8; ++j) {
                const unsigned short h = f2bf(vv[j]);
                bh[j] = (short)h;
                bl[j] = (short)f2bf(vv[j] - bf2f(h));
            }
            Bh[lt][ks] = bh; Bl[lt][ks] = bl;
        }
    }
    const int s = segoff[b];
    const int n = segoff[b + 1] - s;

    float cm0 = -INFINITY, cm1 = -INFINITY;
    for (int t = t0; t * 16 < n; t += 2) {
        const int arow = min(s + t * 16 + col, A_N - 1);
        const unsigned short* xh = Xh + (size_t)arow * D;
        const unsigned short* xl = Xl + (size_t)arow * D;
        short8 Ah[4], Al[4];
        #pragma unroll
        for (int ks = 0; ks < 4; ++ks) {
            Ah[ks] = *(const short8*)(xh + ks * 32 + kb * 8);
            Al[ks] = *(const short8*)(xl + ks * 32 + kb * 8);
        }
        f32x4 a0HH = {0.f,0.f,0.f,0.f}, a0HL = {0.f,0.f,0.f,0.f}, a0LH = {0.f,0.f,0.f,0.f};
        f32x4 a1HH = {0.f,0.f,0.f,0.f}, a1HL = {0.f,0.f,0.f,0.f}, a1LH = {0.f,0.f,0.f,0.f};
        #pragma unroll
        for (int ks = 0; ks < 4; ++ks) {
            a0HH = __builtin_amdgcn_mfma_f32_16x16x32_bf16(Ah[ks], Bh[0][ks], a0HH, 0, 0, 0);
            a0HL = __builtin_amdgcn_mfma_f32_16x16x32_bf16(Ah[ks], Bl[0][ks], a0HL, 0, 0, 0);
            a0LH = __builtin_amdgcn_mfma_f32_16x16x32_bf16(Al[ks], Bh[0][ks], a0LH, 0, 0, 0);
            a1HH = __builtin_amdgcn_mfma_f32_16x16x32_bf16(Ah[ks], Bh[1][ks], a1HH, 0, 0, 0);
            a1HL = __builtin_amdgcn_mfma_f32_16x16x32_bf16(Ah[ks], Bl[1][ks], a1HL, 0, 0, 0);
            a1LH = __builtin_amdgcn_mfma_f32_16x16x32_bf16(Al[ks], Bh[1][ks], a1LH, 0, 0, 0);
        }
        float ra[4], rb[4];
        #pragma unroll
        for (int i = 0; i < 4; ++i) {
            ra[i] = a0HH[i] + a0HL[i] + a0LH[i];
            rb[i] = a1HH[i] + a1HL[i] + a1LH[i];
        }
        // rowmax over this wave's 32 l's (shuffle over col bits)
        float m0 = fmaxf(ra[0], rb[0]), m1 = fmaxf(ra[1], rb[1]);
        float m2 = fmaxf(ra[2], rb[2]), m3 = fmaxf(ra[3], rb[3]);
        #pragma unroll
        for (int off = 1; off <= 8; off <<= 1) {
            m0 = fmaxf(m0, __shfl_xor(m0, off));
            m1 = fmaxf(m1, __shfl_xor(m1, off));
            m2 = fmaxf(m2, __shfl_xor(m2, off));
            m3 = fmaxf(m3, __shfl_xor(m3, off));
        }
        if (col == 0) {
            const int rbase = t * 16 + kb * 4;
            float mm[4] = {m0, m1, m2, m3};
            #pragma unroll
            for (int i = 0; i < 4; ++i)
                if (rbase + i < n)
                    rowmaxp[(size_t)(s + rbase + i) * NCHUNK + chunk] = mm[i];
        }
        // colmax over valid atom rows
        const int rbase = t * 16 + kb * 4;
        float c0 = -INFINITY, c1 = -INFINITY;
        #pragma unroll
        for (int i = 0; i < 4; ++i) {
            if (rbase + i < n) {
                c0 = fmaxf(c0, ra[i]);
                c1 = fmaxf(c1, rb[i]);
            }
        }
        c0 = fmaxf(c0, __shfl_xor(c0, 16)); c0 = fmaxf(c0, __shfl_xor(c0, 32));
        c1 = fmaxf(c1, __shfl_xor(c1, 16)); c1 = fmaxf(c1, __shfl_xor(c1, 32));
        cm0 = fmaxf(cm0, c0);
        cm1 = fmaxf(cm1, c1);
    }
    if (kb == 0) {
        cmaxp[(size_t)(b * 2 + t0) * L_N + l0 + col]      = cm0;
        cmaxp[(size_t)(b * 2 + t0) * L_N + l0 + 16 + col] = cm1;
    }
}

// ---------- K3: pools, 256 blocks = (d-quarter, molecule) -> HcT [256][64] ----------
__global__ __launch_bounds__(256) void k3_pool(const float* __restrict__ atom_embed,
                                               const float* __restrict__ prot,
                                               const int* __restrict__ segoff,
                                               const float* __restrict__ rowmaxp,
                                               const float* __restrict__ cmaxp,
                                               float* __restrict__ HcT) {
    __shared__ float red[4];
    __shared__ float coef[512];
    __shared__ float ews_s[L_N];
    __shared__ float4 pred[32][8];
    const int tid = threadIdx.x;
    const int bid = blockIdx.x;
    const int b = bid & (B_N - 1);
    const int dq = bid >> 6;        // d-quarter 0..3
    const int s = segoff[b];
    const int n = segoff[b + 1] - s;

    // Sc = sum_a exp(max over chunks)
    float local = 0.f;
    for (int j = tid; j < n; j += 256) {
        const float* rp = rowmaxp + (size_t)(s + j) * NCHUNK;
        float m = rp[0];
        #pragma unroll
        for (int c = 1; c < NCHUNK; ++c) m = fmaxf(m, rp[c]);
        local += expf(m);
    }
    const float Sc = blk_sum(local, red, tid);

    // ews[l] + Z
    float lz = 0.f;
    for (int l = tid; l < L_N; l += 256) {
        const float m = fmaxf(cmaxp[(size_t)(b * 2) * L_N + l],
                              cmaxp[(size_t)(b * 2 + 1) * L_N + l]);
        const float e = expf(m);
        ews_s[l] = e;
        lz += e;
    }
    const float Z = blk_sum(lz, red, tid);   // syncs -> ews_s visible

    const int d8 = tid & 7;    // float4 within 32-dim slice
    const int rg = tid >> 3;   // 0..31 row group

    // atom pool slice
    const float4* ae4 = (const float4*)atom_embed;
    float4 pool = {0.f, 0.f, 0.f, 0.f};
    for (int base = 0; base < n; base += 512) {
        const int cnt = min(512, n - base);
        __syncthreads();
        for (int j = tid; j < cnt; j += 256) {
            const float* rp = rowmaxp + (size_t)(s + base + j) * NCHUNK;
            float m = rp[0];
            #pragma unroll
            for (int c = 1; c < NCHUNK; ++c) m = fmaxf(m, rp[c]);
            coef[j] = expf(m) / Sc;
        }
        __syncthreads();
        #pragma unroll 2
        for (int j = rg; j < cnt; j += 32) {
            const float c = coef[j];
            const float4 v = ae4[(size_t)(s + base + j) * (D / 4) + dq * 8 + d8];
            pool.x += c * v.x; pool.y += c * v.y; pool.z += c * v.z; pool.w += c * v.w;
        }
    }

    // prot pool slice (coalesced 128B row-slices, streamed once)
    const float4* pr4 = (const float4*)prot;
    float4 pp = {0.f, 0.f, 0.f, 0.f};
    #pragma unroll 4
    for (int l = rg; l < L_N; l += 32) {
        const float wgt = ews_s[l];
        const float4 v = pr4[((size_t)b * L_N + l) * (D / 4) + dq * 8 + d8];
        pp.x += wgt * v.x; pp.y += wgt * v.y; pp.z += wgt * v.z; pp.w += wgt * v.w;
    }

    // reduce atom pool over 32 row-groups
    __syncthreads();
    pred[rg][d8] = pool;
    __syncthreads();
    if (rg < 8) {
        float4 a = pred[rg][d8];
        #pragma unroll
        for (int k = 1; k < 4; ++k) {
            const float4 t = pred[rg + 8 * k][d8];
            a.x += t.x; a.y += t.y; a.z += t.z; a.w += t.w;
        }
        pred[rg][d8] = a;
    }
    __syncthreads();
    if (tid < 8) {
        float4 a = pred[0][tid];
        #pragma unroll
        for (int g = 1; g < 8; ++g) {
            const float4 t = pred[g][tid];
            a.x += t.x; a.y += t.y; a.z += t.z; a.w += t.w;
        }
        const int dbase = dq * 32 + tid * 4;
        HcT[(size_t)(dbase + 0) * B_N + b] = a.x;
        HcT[(size_t)(dbase + 1) * B_N + b] = a.y;
        HcT[(size_t)(dbase + 2) * B_N + b] = a.z;
        HcT[(size_t)(dbase + 3) * B_N + b] = a.w;
    }
    // reduce prot pool
    __syncthreads();
    pred[rg][d8] = pp;
    __syncthreads();
    if (rg < 8) {
        float4 a = pred[rg][d8];
        #pragma unroll
        for (int k = 1; k < 4; ++k) {
            const float4 t = pred[rg + 8 * k][d8];
            a.x += t.x; a.y += t.y; a.z += t.z; a.w += t.w;
        }
        pred[rg][d8] = a;
    }
    __syncthreads();
    if (tid < 8) {
        float4 a = pred[0][tid];
        #pragma unroll
        for (int g = 1; g < 8; ++g) {
            const float4 t = pred[g][tid];
            a.x += t.x; a.y += t.y; a.z += t.z; a.w += t.w;
        }
        const float invZ = 1.f / Z;
        const int dbase = D + dq * 32 + tid * 4;
        HcT[(size_t)(dbase + 0) * B_N + b] = a.x * invZ;
        HcT[(size_t)(dbase + 1) * B_N + b] = a.y * invZ;
        HcT[(size_t)(dbase + 2) * B_N + b] = a.z * invZ;
        HcT[(size_t)(dbase + 3) * B_N + b] = a.w * invZ;
    }
}

// ---------- K4: H1T = relu(Hc @ W1 + b1)^T ----------
__global__ __launch_bounds__(256) void k4_h1(const float* __restrict__ HcT,
                                             const float* __restrict__ W1,
                                             const float* __restrict__ b1,
                                             float* __restrict__ H1T) {
    __shared__ float hr[4][64];
    const int tid = threadIdx.x;
    const int m = tid & 63;
    const int jh = (tid >> 6) & 1;
    const int kh = tid >> 7;
    const int j = blockIdx.x * 2 + jh;
    float acc = 0.f;
    const int k0 = kh * 128;
    #pragma unroll 8
    for (int k = k0; k < k0 + 128; ++k)
        acc += HcT[(size_t)k * B_N + m] * W1[(size_t)k * H1_N + j];
    hr[jh * 2 + kh][m] = acc;
    __syncthreads();
    if (kh == 0)
        H1T[(size_t)j * B_N + m] = fmaxf(hr[jh * 2][m] + hr[jh * 2 + 1][m] + b1[j], 0.f);
}

// ---------- K5: H2 + output atomics ----------
__global__ __launch_bounds__(256) void k5_h2(const float* __restrict__ H1T,
                                             const float* __restrict__ W2,
                                             const float* __restrict__ b2,
                                             const float* __restrict__ Wo,
                                             float* __restrict__ out) {
    __shared__ float hr[4][64];
    const int tid = threadIdx.x;
    const int m = tid & 63;
    const int kq = tid >> 6;
    const int j = blockIdx.x;
    float acc = 0.f;
    const int k0 = kq * 128;
    #pragma unroll 8
    for (int k = k0; k < k0 + 128; ++k)
        acc += H1T[(size_t)k * B_N + m] * W2[(size_t)k * H2_N + j];
    hr[kq][m] = acc;
    __syncthreads();
    if (kq == 0) {
        const float h2 = fmaxf(hr[0][m] + hr[1][m] + hr[2][m] + hr[3][m] + b2[j], 0.f);
        atomicAdd(out + m, h2 * Wo[j]);
    }
}

extern "C" void kernel_launch(void* const* d_in, const int* in_sizes, int n_in,
                              void* d_out, int out_size, void* d_ws, size_t ws_size,
                              hipStream_t stream) {
    const float* atom_embed = (const float*)d_in[0];
    const float* prot       = (const float*)d_in[1];
    const int*   splits     = (const int*)d_in[2];
    const float* W_att      = (const float*)d_in[3];
    const float* W1         = (const float*)d_in[4];
    const float* b1         = (const float*)d_in[5];
    const float* W2         = (const float*)d_in[6];
    const float* b2         = (const float*)d_in[7];
    const float* Wo         = (const float*)d_in[8];
    const float* bo         = (const float*)d_in[9];
    float* out = (float*)d_out;

    unsigned short* Xh = (unsigned short*)d_ws;                // A_N*D ushort
    unsigned short* Xl = Xh + (size_t)A_N * D;                 // A_N*D ushort
    float* fp      = (float*)(Xl + (size_t)A_N * D);
    float* rowmaxp = fp;  fp += (size_t)A_N * NCHUNK;          // 32768 f
    float* cmaxp   = fp;  fp += (size_t)B_N * 2 * L_N;         // 65536 f
    float* HcT     = fp;  fp += 2 * D * B_N;                   // 16384 f
    float* H1T     = fp;  fp += H1_N * B_N;                    // 32768 f
    int*   segoff  = (int*)fp;                                 // 65 ints

    hipLaunchKernelGGL(k1_xmul,  dim3(A_N / 8),   dim3(256), 0, stream,
                       atom_embed, W_att, bo, splits, Xh, Xl, out, segoff);
    hipLaunchKernelGGL(k2_scores, dim3(512),      dim3(256), 0, stream,
                       Xh, Xl, prot, segoff, rowmaxp, cmaxp);
    hipLaunchKernelGGL(k3_pool,  dim3(4 * B_N),   dim3(256), 0, stream,
                       atom_embed, prot, segoff, rowmaxp, cmaxp, HcT);
    hipLaunchKernelGGL(k4_h1,    dim3(H1_N / 2),  dim3(256), 0, stream, HcT, W1, b1, H1T);
    hipLaunchKernelGGL(k5_h2,    dim3(H2_N),      dim3(256), 0, stream, H1T, W2, b2, Wo, out);
}

// Round 12
// 44.447 us; speedup vs baseline: 2.0465x; 1.0598x over previous
//
#include <hip/hip_runtime.h>
#include <math.h>

#define A_N 2048
#define L_N 512
#define D 128
#define B_N 64
#define H1_N 512
#define H2_N 256
#define NCHUNK 16

typedef __attribute__((ext_vector_type(8))) short short8;
typedef __attribute__((ext_vector_type(4))) float f32x4;

__device__ __forceinline__ int lb_dev(const int* __restrict__ arr, int n, int val) {
    int lo = 0, hi = n;
    while (lo < hi) { int mid = (lo + hi) >> 1; if (arr[mid] < val) lo = mid + 1; else hi = mid; }
    return lo;
}

__device__ __forceinline__ float blk_sum(float v, float* red, int tid) {
    #pragma unroll
    for (int off = 32; off >= 1; off >>= 1) v += __shfl_xor(v, off);
    __syncthreads();
    if ((tid & 63) == 0) red[tid >> 6] = v;
    __syncthreads();
    return red[0] + red[1] + red[2] + red[3];
}

__device__ __forceinline__ unsigned short f2bf(float f) {
    unsigned int u = __float_as_uint(f);
    return (unsigned short)((u + 0x7FFFu + ((u >> 16) & 1u)) >> 16);
}
__device__ __forceinline__ float bf2f(unsigned short h) {
    return __uint_as_float(((unsigned int)h) << 16);
}

// ---------- K1: X = atom_embed @ W_att via split-bf16 MFMA -> Xh/Xl ----------
// 128 blocks x 16 atom rows; wave w owns d-coltiles {2w, 2w+1}. No LDS.
__global__ __launch_bounds__(256) void k1_xmul(const float* __restrict__ atom_embed,
                                               const float* __restrict__ W_att,
                                               const float* __restrict__ bo,
                                               const int* __restrict__ splits,
                                               unsigned short* __restrict__ Xh,
                                               unsigned short* __restrict__ Xl,
                                               float* __restrict__ out,
                                               int* __restrict__ segoff) {
    const int tid = threadIdx.x;
    const int bid = blockIdx.x;
    if (bid == 0) {
        if (tid <= B_N) segoff[tid] = lb_dev(splits, A_N, tid);
        if (tid < B_N) out[tid] = bo[0];
    }
    const int lane = tid & 63;
    const int w = tid >> 6;
    const int col = lane & 15;
    const int kb = lane >> 4;
    const int r0 = bid * 16;

    // A-frags: atom rows r0+col, k-slice ks*32+kb*8 (8 coalesced float4 loads)
    short8 Ah[4], Al[4];
    {
        const float4* p = (const float4*)(atom_embed + (size_t)(r0 + col) * D);
        #pragma unroll
        for (int ks = 0; ks < 4; ++ks) {
            const float4 v0 = p[ks * 8 + kb * 2];
            const float4 v1 = p[ks * 8 + kb * 2 + 1];
            const float vv[8] = {v0.x, v0.y, v0.z, v0.w, v1.x, v1.y, v1.z, v1.w};
            short8 ah, al;
            #pragma unroll
            for (int j = 0; j < 8; ++j) {
                const unsigned short h = f2bf(vv[j]);
                ah[j] = (short)h;
                al[j] = (short)f2bf(vv[j] - bf2f(h));
            }
            Ah[ks] = ah; Al[ks] = al;
        }
    }

    #pragma unroll
    for (int ct = 0; ct < 2; ++ct) {
        const int dcol = (w * 2 + ct) * 16 + col;
        // B-frags = W_att columns dcol (L2-hot strided gather)
        short8 Bh[4], Bl[4];
        #pragma unroll
        for (int ks = 0; ks < 4; ++ks) {
            short8 bh, bl;
            #pragma unroll
            for (int j = 0; j < 8; ++j) {
                const float wv = W_att[(size_t)(ks * 32 + kb * 8 + j) * D + dcol];
                const unsigned short h = f2bf(wv);
                bh[j] = (short)h;
                bl[j] = (short)f2bf(wv - bf2f(h));
            }
            Bh[ks] = bh; Bl[ks] = bl;
        }
        f32x4 aHH = {0.f, 0.f, 0.f, 0.f};
        f32x4 aHL = {0.f, 0.f, 0.f, 0.f};
        f32x4 aLH = {0.f, 0.f, 0.f, 0.f};
        #pragma unroll
        for (int ks = 0; ks < 4; ++ks) {
            aHH = __builtin_amdgcn_mfma_f32_16x16x32_bf16(Ah[ks], Bh[ks], aHH, 0, 0, 0);
            aHL = __builtin_amdgcn_mfma_f32_16x16x32_bf16(Ah[ks], Bl[ks], aHL, 0, 0, 0);
            aLH = __builtin_amdgcn_mfma_f32_16x16x32_bf16(Al[ks], Bh[ks], aLH, 0, 0, 0);
        }
        #pragma unroll
        for (int i = 0; i < 4; ++i) {
            const float xv = aHH[i] + aHL[i] + aLH[i];
            const size_t idx = (size_t)(r0 + kb * 4 + i) * D + dcol;
            const unsigned short h = f2bf(xv);
            Xh[idx] = h;
            Xl[idx] = f2bf(xv - bf2f(h));
        }
    }
}

// ---------- K2: barrier-free wave-parallel MFMA scores ----------
// 512 blocks x 4 independent waves = 2048 waves; wave = (b, chunk, tile-parity t0)
__global__ __launch_bounds__(256) void k2_scores(const unsigned short* __restrict__ Xh,
                                                 const unsigned short* __restrict__ Xl,
                                                 const float* __restrict__ prot,
                                                 const int* __restrict__ segoff,
                                                 float* __restrict__ rowmaxp,
                                                 float* __restrict__ cmaxp) {
    const int tid = threadIdx.x;
    const int bid = blockIdx.x;
    const int b = bid & (B_N - 1);                 // bid%8 == b%8 -> per-molecule XCD locality
    const int unit = (bid >> 6) * 4 + (tid >> 6);  // 0..31
    const int chunk = unit & 15;
    const int t0 = unit >> 4;                      // 0..1
    const int lane = tid & 63;
    const int col = lane & 15;
    const int kb = lane >> 4;
    const int l0 = chunk * 32;

    // B-frags for 2 l-tiles, loaded once (unrolled -> 16 loads in flight)
    short8 Bh[2][4], Bl[2][4];
    #pragma unroll
    for (int lt = 0; lt < 2; ++lt) {
        const float4* pb = (const float4*)(prot + ((size_t)(b * L_N + l0 + lt * 16 + col)) * D);
        #pragma unroll
        for (int ks = 0; ks < 4; ++ks) {
            const float4 v0 = pb[ks * 8 + kb * 2];
            const float4 v1 = pb[ks * 8 + kb * 2 + 1];
            const float vv[8] = {v0.x, v0.y, v0.z, v0.w, v1.x, v1.y, v1.z, v1.w};
            short8 bh, bl;
            #pragma unroll
            for (int j = 0; j < 8; ++j) {
                const unsigned short h = f2bf(vv[j]);
                bh[j] = (short)h;
                bl[j] = (short)f2bf(vv[j] - bf2f(h));
            }
            Bh[lt][ks] = bh; Bl[lt][ks] = bl;
        }
    }
    const int s = segoff[b];
    const int n = segoff[b + 1] - s;

    float cm0 = -INFINITY, cm1 = -INFINITY;
    for (int t = t0; t * 16 < n; t += 2) {
        const int arow = min(s + t * 16 + col, A_N - 1);
        const unsigned short* xh = Xh + (size_t)arow * D;
        const unsigned short* xl = Xl + (size_t)arow * D;
        short8 Ah[4], Al[4];
        #pragma unroll
        for (int ks = 0; ks < 4; ++ks) {
            Ah[ks] = *(const short8*)(xh + ks * 32 + kb * 8);
            Al[ks] = *(const short8*)(xl + ks * 32 + kb * 8);
        }
        f32x4 a0HH = {0.f,0.f,0.f,0.f}, a0HL = {0.f,0.f,0.f,0.f}, a0LH = {0.f,0.f,0.f,0.f};
        f32x4 a1HH = {0.f,0.f,0.f,0.f}, a1HL = {0.f,0.f,0.f,0.f}, a1LH = {0.f,0.f,0.f,0.f};
        #pragma unroll
        for (int ks = 0; ks < 4; ++ks) {
            a0HH = __builtin_amdgcn_mfma_f32_16x16x32_bf16(Ah[ks], Bh[0][ks], a0HH, 0, 0, 0);
            a0HL = __builtin_amdgcn_mfma_f32_16x16x32_bf16(Ah[ks], Bl[0][ks], a0HL, 0, 0, 0);
            a0LH = __builtin_amdgcn_mfma_f32_16x16x32_bf16(Al[ks], Bh[0][ks], a0LH, 0, 0, 0);
            a1HH = __builtin_amdgcn_mfma_f32_16x16x32_bf16(Ah[ks], Bh[1][ks], a1HH, 0, 0, 0);
            a1HL = __builtin_amdgcn_mfma_f32_16x16x32_bf16(Ah[ks], Bl[1][ks], a1HL, 0, 0, 0);
            a1LH = __builtin_amdgcn_mfma_f32_16x16x32_bf16(Al[ks], Bh[1][ks], a1LH, 0, 0, 0);
        }
        float ra[4], rb[4];
        #pragma unroll
        for (int i = 0; i < 4; ++i) {
            ra[i] = a0HH[i] + a0HL[i] + a0LH[i];
            rb[i] = a1HH[i] + a1HL[i] + a1LH[i];
        }
        // rowmax over this wave's 32 l's (shuffle over col bits)
        float m0 = fmaxf(ra[0], rb[0]), m1 = fmaxf(ra[1], rb[1]);
        float m2 = fmaxf(ra[2], rb[2]), m3 = fmaxf(ra[3], rb[3]);
        #pragma unroll
        for (int off = 1; off <= 8; off <<= 1) {
            m0 = fmaxf(m0, __shfl_xor(m0, off));
            m1 = fmaxf(m1, __shfl_xor(m1, off));
            m2 = fmaxf(m2, __shfl_xor(m2, off));
            m3 = fmaxf(m3, __shfl_xor(m3, off));
        }
        if (col == 0) {
            const int rbase = t * 16 + kb * 4;
            float mm[4] = {m0, m1, m2, m3};
            #pragma unroll
            for (int i = 0; i < 4; ++i)
                if (rbase + i < n)
                    rowmaxp[(size_t)(s + rbase + i) * NCHUNK + chunk] = mm[i];
        }
        // colmax over valid atom rows
        const int rbase = t * 16 + kb * 4;
        float c0 = -INFINITY, c1 = -INFINITY;
        #pragma unroll
        for (int i = 0; i < 4; ++i) {
            if (rbase + i < n) {
                c0 = fmaxf(c0, ra[i]);
                c1 = fmaxf(c1, rb[i]);
            }
        }
        c0 = fmaxf(c0, __shfl_xor(c0, 16)); c0 = fmaxf(c0, __shfl_xor(c0, 32));
        c1 = fmaxf(c1, __shfl_xor(c1, 16)); c1 = fmaxf(c1, __shfl_xor(c1, 32));
        cm0 = fmaxf(cm0, c0);
        cm1 = fmaxf(cm1, c1);
    }
    if (kb == 0) {
        cmaxp[(size_t)(b * 2 + t0) * L_N + l0 + col]      = cm0;
        cmaxp[(size_t)(b * 2 + t0) * L_N + l0 + 16 + col] = cm1;
    }
}

// ---------- K3: pools, 256 blocks = (d-quarter, molecule) -> HcT [256][64] ----------
__global__ __launch_bounds__(256) void k3_pool(const float* __restrict__ atom_embed,
                                               const float* __restrict__ prot,
                                               const int* __restrict__ segoff,
                                               const float* __restrict__ rowmaxp,
                                               const float* __restrict__ cmaxp,
                                               float* __restrict__ HcT) {
    __shared__ float red[4];
    __shared__ float coef[512];
    __shared__ float ews_s[L_N];
    __shared__ float4 pred[32][8];
    const int tid = threadIdx.x;
    const int bid = blockIdx.x;
    const int b = bid & (B_N - 1);
    const int dq = bid >> 6;        // d-quarter 0..3
    const int s = segoff[b];
    const int n = segoff[b + 1] - s;

    // Sc = sum_a exp(max over chunks)
    float local = 0.f;
    for (int j = tid; j < n; j += 256) {
        const float* rp = rowmaxp + (size_t)(s + j) * NCHUNK;
        float m = rp[0];
        #pragma unroll
        for (int c = 1; c < NCHUNK; ++c) m = fmaxf(m, rp[c]);
        local += expf(m);
    }
    const float Sc = blk_sum(local, red, tid);

    // ews[l] + Z
    float lz = 0.f;
    for (int l = tid; l < L_N; l += 256) {
        const float m = fmaxf(cmaxp[(size_t)(b * 2) * L_N + l],
                              cmaxp[(size_t)(b * 2 + 1) * L_N + l]);
        const float e = expf(m);
        ews_s[l] = e;
        lz += e;
    }
    const float Z = blk_sum(lz, red, tid);   // syncs -> ews_s visible

    const int d8 = tid & 7;    // float4 within 32-dim slice
    const int rg = tid >> 3;   // 0..31 row group

    // atom pool slice
    const float4* ae4 = (const float4*)atom_embed;
    float4 pool = {0.f, 0.f, 0.f, 0.f};
    for (int base = 0; base < n; base += 512) {
        const int cnt = min(512, n - base);
        __syncthreads();
        for (int j = tid; j < cnt; j += 256) {
            const float* rp = rowmaxp + (size_t)(s + base + j) * NCHUNK;
            float m = rp[0];
            #pragma unroll
            for (int c = 1; c < NCHUNK; ++c) m = fmaxf(m, rp[c]);
            coef[j] = expf(m) / Sc;
        }
        __syncthreads();
        #pragma unroll 2
        for (int j = rg; j < cnt; j += 32) {
            const float c = coef[j];
            const float4 v = ae4[(size_t)(s + base + j) * (D / 4) + dq * 8 + d8];
            pool.x += c * v.x; pool.y += c * v.y; pool.z += c * v.z; pool.w += c * v.w;
        }
    }

    // prot pool slice (coalesced 128B row-slices, streamed once)
    const float4* pr4 = (const float4*)prot;
    float4 pp = {0.f, 0.f, 0.f, 0.f};
    #pragma unroll 4
    for (int l = rg; l < L_N; l += 32) {
        const float wgt = ews_s[l];
        const float4 v = pr4[((size_t)b * L_N + l) * (D / 4) + dq * 8 + d8];
        pp.x += wgt * v.x; pp.y += wgt * v.y; pp.z += wgt * v.z; pp.w += wgt * v.w;
    }

    // reduce atom pool over 32 row-groups
    __syncthreads();
    pred[rg][d8] = pool;
    __syncthreads();
    if (rg < 8) {
        float4 a = pred[rg][d8];
        #pragma unroll
        for (int k = 1; k < 4; ++k) {
            const float4 t = pred[rg + 8 * k][d8];
            a.x += t.x; a.y += t.y; a.z += t.z; a.w += t.w;
        }
        pred[rg][d8] = a;
    }
    __syncthreads();
    if (tid < 8) {
        float4 a = pred[0][tid];
        #pragma unroll
        for (int g = 1; g < 8; ++g) {
            const float4 t = pred[g][tid];
            a.x += t.x; a.y += t.y; a.z += t.z; a.w += t.w;
        }
        const int dbase = dq * 32 + tid * 4;
        HcT[(size_t)(dbase + 0) * B_N + b] = a.x;
        HcT[(size_t)(dbase + 1) * B_N + b] = a.y;
        HcT[(size_t)(dbase + 2) * B_N + b] = a.z;
        HcT[(size_t)(dbase + 3) * B_N + b] = a.w;
    }
    // reduce prot pool
    __syncthreads();
    pred[rg][d8] = pp;
    __syncthreads();
    if (rg < 8) {
        float4 a = pred[rg][d8];
        #pragma unroll
        for (int k = 1; k < 4; ++k) {
            const float4 t = pred[rg + 8 * k][d8];
            a.x += t.x; a.y += t.y; a.z += t.z; a.w += t.w;
        }
        pred[rg][d8] = a;
    }
    __syncthreads();
    if (tid < 8) {
        float4 a = pred[0][tid];
        #pragma unroll
        for (int g = 1; g < 8; ++g) {
            const float4 t = pred[g][tid];
            a.x += t.x; a.y += t.y; a.z += t.z; a.w += t.w;
        }
        const float invZ = 1.f / Z;
        const int dbase = D + dq * 32 + tid * 4;
        HcT[(size_t)(dbase + 0) * B_N + b] = a.x * invZ;
        HcT[(size_t)(dbase + 1) * B_N + b] = a.y * invZ;
        HcT[(size_t)(dbase + 2) * B_N + b] = a.z * invZ;
        HcT[(size_t)(dbase + 3) * B_N + b] = a.w * invZ;
    }
}

// ---------- K4: H1T = relu(Hc @ W1 + b1)^T ----------
__global__ __launch_bounds__(256) void k4_h1(const float* __restrict__ HcT,
                                             const float* __restrict__ W1,
                                             const float* __restrict__ b1,
                                             float* __restrict__ H1T) {
    __shared__ float hr[4][64];
    const int tid = threadIdx.x;
    const int m = tid & 63;
    const int jh = (tid >> 6) & 1;
    const int kh = tid >> 7;
    const int j = blockIdx.x * 2 + jh;
    float acc = 0.f;
    const int k0 = kh * 128;
    #pragma unroll 8
    for (int k = k0; k < k0 + 128; ++k)
        acc += HcT[(size_t)k * B_N + m] * W1[(size_t)k * H1_N + j];
    hr[jh * 2 + kh][m] = acc;
    __syncthreads();
    if (kh == 0)
        H1T[(size_t)j * B_N + m] = fmaxf(hr[jh * 2][m] + hr[jh * 2 + 1][m] + b1[j], 0.f);
}

// ---------- K5: H2 + output atomics ----------
__global__ __launch_bounds__(256) void k5_h2(const float* __restrict__ H1T,
                                             const float* __restrict__ W2,
                                             const float* __restrict__ b2,
                                             const float* __restrict__ Wo,
                                             float* __restrict__ out) {
    __shared__ float hr[4][64];
    const int tid = threadIdx.x;
    const int m = tid & 63;
    const int kq = tid >> 6;
    const int j = blockIdx.x;
    float acc = 0.f;
    const int k0 = kq * 128;
    #pragma unroll 8
    for (int k = k0; k < k0 + 128; ++k)
        acc += H1T[(size_t)k * B_N + m] * W2[(size_t)k * H2_N + j];
    hr[kq][m] = acc;
    __syncthreads();
    if (kq == 0) {
        const float h2 = fmaxf(hr[0][m] + hr[1][m] + hr[2][m] + hr[3][m] + b2[j], 0.f);
        atomicAdd(out + m, h2 * Wo[j]);
    }
}

extern "C" void kernel_launch(void* const* d_in, const int* in_sizes, int n_in,
                              void* d_out, int out_size, void* d_ws, size_t ws_size,
                              hipStream_t stream) {
    const float* atom_embed = (const float*)d_in[0];
    const float* prot       = (const float*)d_in[1];
    const int*   splits     = (const int*)d_in[2];
    const float* W_att      = (const float*)d_in[3];
    const float* W1         = (const float*)d_in[4];
    const float* b1         = (const float*)d_in[5];
    const float* W2         = (const float*)d_in[6];
    const float* b2         = (const float*)d_in[7];
    const float* Wo         = (const float*)d_in[8];
    const float* bo         = (const float*)d_in[9];
    float* out = (float*)d_out;

    unsigned short* Xh = (unsigned short*)d_ws;                // A_N*D ushort
    unsigned short* Xl = Xh + (size_t)A_N * D;                 // A_N*D ushort
    float* fp      = (float*)(Xl + (size_t)A_N * D);
    float* rowmaxp = fp;  fp += (size_t)A_N * NCHUNK;          // 32768 f
    float* cmaxp   = fp;  fp += (size_t)B_N * 2 * L_N;         // 65536 f
    float* HcT     = fp;  fp += 2 * D * B_N;                   // 16384 f
    float* H1T     = fp;  fp += H1_N * B_N;                    // 32768 f
    int*   segoff  = (int*)fp;                                 // 65 ints

    hipLaunchKernelGGL(k1_xmul,  dim3(A_N / 16),  dim3(256), 0, stream,
                       atom_embed, W_att, bo, splits, Xh, Xl, out, segoff);
    hipLaunchKernelGGL(k2_scores, dim3(512),      dim3(256), 0, stream,
                       Xh, Xl, prot, segoff, rowmaxp, cmaxp);
    hipLaunchKernelGGL(k3_pool,  dim3(4 * B_N),   dim3(256), 0, stream,
                       atom_embed, prot, segoff, rowmaxp, cmaxp, HcT);
    hipLaunchKernelGGL(k4_h1,    dim3(H1_N / 2),  dim3(256), 0, stream, HcT, W1, b1, H1T);
    hipLaunchKernelGGL(k5_h2,    dim3(H2_N),      dim3(256), 0, stream, H1T, W2, b2, Wo, out);
}